// Round 1
// baseline (2152.726 us; speedup 1.0000x reference)
//
#include <hip/hip_runtime.h>
#include <math.h>

#define NXR 8192
#define NCR 8192
#define HD  512

// ---------------------------------------------------------------------------
// Generic MLP layer: Y[N x M] = act(X[N x K] @ W[K x M] + b[M])
// ACT: 0 = identity, 1 = sin
// Tiling: 64x64 output tile per block (256 threads, 4x4 micro-tile), BK=16.
// Handles K=3 (first layer) and M=3 (V output) via zero-pad guards.
// ---------------------------------------------------------------------------
template<int ACT>
__global__ __launch_bounds__(256) void mlp_layer(
    const float* __restrict__ X, const float* __restrict__ W,
    const float* __restrict__ b, float* __restrict__ Y,
    int N, int K, int M)
{
    const int BM = 64, BN = 64, BK = 16;
    const int PAD = 4;                 // row stride 68 floats: 16B-aligned rows
    __shared__ float Xs[BK][BM + PAD]; // transposed: Xs[k][m]
    __shared__ float Ws[BK][BN + PAD]; // Ws[k][n]

    const int tid = threadIdx.x;
    const int tx = tid & 15;
    const int ty = tid >> 4;
    const int row0 = blockIdx.x * BM;
    const int col0 = blockIdx.y * BN;

    float acc[4][4] = {};

    for (int kt = 0; kt < K; kt += BK) {
#pragma unroll
        for (int l = 0; l < 4; ++l) {
            int idx = tid + l * 256;           // 0..1023
            // X tile: BM x BK -> store transposed
            int m  = idx >> 4;                 // /BK
            int kk = idx & 15;                 // %BK
            int gk = kt + kk;
            float v = 0.f;
            if (gk < K) v = X[(size_t)(row0 + m) * K + gk];
            Xs[kk][m] = v;
            // W tile: BK x BN
            int n  = idx & 63;                 // %BN
            int k2 = idx >> 6;                 // /BN (0..15)
            int gk2 = kt + k2, gn = col0 + n;
            float w = 0.f;
            if (gk2 < K && gn < M) w = W[(size_t)gk2 * M + gn];
            Ws[k2][n] = w;
        }
        __syncthreads();

#pragma unroll
        for (int kk = 0; kk < BK; ++kk) {
            float a[4], bb[4];
#pragma unroll
            for (int i = 0; i < 4; ++i) a[i]  = Xs[kk][ty * 4 + i];
#pragma unroll
            for (int j = 0; j < 4; ++j) bb[j] = Ws[kk][tx * 4 + j];
#pragma unroll
            for (int i = 0; i < 4; ++i)
#pragma unroll
                for (int j = 0; j < 4; ++j)
                    acc[i][j] += a[i] * bb[j];
        }
        __syncthreads();
    }

#pragma unroll
    for (int i = 0; i < 4; ++i) {
        int r = row0 + ty * 4 + i;
#pragma unroll
        for (int j = 0; j < 4; ++j) {
            int ccol = col0 + tx * 4 + j;
            if (ccol < M) {
                float v = acc[i][j] + b[ccol];
                if (ACT == 1) v = sinf(v);
                Y[(size_t)r * M + ccol] = v;
            }
        }
    }
}

// ---------------------------------------------------------------------------
// Fused attention: out[i,:] += sum_j sigmoid(q_i . k_j) * V[j,:]
// Block: 64 Q-rows x (NC/jslices) K-rows. 64x64 S-tile per j-step, fp32.
// Per-thread partial out accumulator [4 rows][3], shuffle-reduced over tx,
// atomically added into out (out must be zeroed beforehand).
// ---------------------------------------------------------------------------
__global__ __launch_bounds__(256) void attn_fused(
    const float* __restrict__ Q, const float* __restrict__ Km,
    const float* __restrict__ V, float* __restrict__ out, int jslices)
{
    const int BM = 64, BJ = 64, BK = 16, D = HD;
    const int PAD = 4;
    __shared__ float Qs[BK][BM + PAD];
    __shared__ float Ks[BK][BJ + PAD];
    __shared__ float Vs[BJ][3];

    const int tid = threadIdx.x;
    const int tx = tid & 15;
    const int ty = tid >> 4;
    const int row0 = blockIdx.x * BM;
    const int jcount = NCR / jslices;
    const int jbase = blockIdx.y * jcount;

    float po[4][3] = {};

    for (int jt = 0; jt < jcount; jt += BJ) {
        const int j0 = jbase + jt;
        float acc[4][4] = {};

        for (int dt = 0; dt < D; dt += BK) {
#pragma unroll
            for (int l = 0; l < 4; ++l) {
                int idx = tid + l * 256;
                int m  = idx >> 4;
                int kk = idx & 15;
                Qs[kk][m] = Q [(size_t)(row0 + m) * D + dt + kk];
                Ks[kk][m] = Km[(size_t)(j0   + m) * D + dt + kk];
            }
            __syncthreads();
#pragma unroll
            for (int kk = 0; kk < BK; ++kk) {
                float a[4], bb[4];
#pragma unroll
                for (int i = 0; i < 4; ++i) a[i]  = Qs[kk][ty * 4 + i];
#pragma unroll
                for (int j = 0; j < 4; ++j) bb[j] = Ks[kk][tx * 4 + j];
#pragma unroll
                for (int i = 0; i < 4; ++i)
#pragma unroll
                    for (int j = 0; j < 4; ++j)
                        acc[i][j] += a[i] * bb[j];
            }
            __syncthreads();
        }

        if (tid < BJ * 3) {
            Vs[tid / 3][tid % 3] = V[(size_t)j0 * 3 + tid];
        }
        __syncthreads();

#pragma unroll
        for (int i = 0; i < 4; ++i) {
#pragma unroll
            for (int j = 0; j < 4; ++j) {
                float s = 1.f / (1.f + __expf(-acc[i][j]));
                int jj = tx * 4 + j;
#pragma unroll
                for (int c = 0; c < 3; ++c) po[i][c] += s * Vs[jj][c];
            }
        }
        __syncthreads();
    }

    // Reduce po across the 16 tx lanes of each ty group (lanes grouped by 16).
#pragma unroll
    for (int i = 0; i < 4; ++i) {
#pragma unroll
        for (int c = 0; c < 3; ++c) {
            float v = po[i][c];
            v += __shfl_down(v, 8, 16);
            v += __shfl_down(v, 4, 16);
            v += __shfl_down(v, 2, 16);
            v += __shfl_down(v, 1, 16);
            if (tx == 0)
                atomicAdd(&out[(size_t)(row0 + ty * 4 + i) * 3 + c], v);
        }
    }
}

// ---------------------------------------------------------------------------
static void run_mlp(const float* X, int N, int in_dim,
                    const float* W0, const float* b0,
                    const float* Wh, const float* bh,
                    const float* Wo, const float* bo,
                    int out_dim, float* h1, float* h2, float* out,
                    hipStream_t stream)
{
    dim3 blk(256);
    dim3 gh(N / 64, HD / 64);
    mlp_layer<1><<<gh, blk, 0, stream>>>(X,  W0,               b0,           h1, N, in_dim, HD);
    mlp_layer<1><<<gh, blk, 0, stream>>>(h1, Wh + 0 * HD * HD, bh + 0 * HD,  h2, N, HD, HD);
    mlp_layer<1><<<gh, blk, 0, stream>>>(h2, Wh + 1 * HD * HD, bh + 1 * HD,  h1, N, HD, HD);
    mlp_layer<1><<<gh, blk, 0, stream>>>(h1, Wh + 2 * HD * HD, bh + 2 * HD,  h2, N, HD, HD);
    dim3 go(N / 64, (out_dim + 63) / 64);
    mlp_layer<0><<<go, blk, 0, stream>>>(h2, Wo,               bo,          out, N, HD, out_dim);
}

extern "C" void kernel_launch(void* const* d_in, const int* in_sizes, int n_in,
                              void* d_out, int out_size, void* d_ws, size_t ws_size,
                              hipStream_t stream)
{
    const float* x   = (const float*)d_in[0];
    const float* c   = (const float*)d_in[1];
    const float* QW0 = (const float*)d_in[2];
    const float* Qb0 = (const float*)d_in[3];
    const float* QWh = (const float*)d_in[4];
    const float* Qbh = (const float*)d_in[5];
    const float* QWo = (const float*)d_in[6];
    const float* Qbo = (const float*)d_in[7];
    const float* KW0 = (const float*)d_in[8];
    const float* Kb0 = (const float*)d_in[9];
    const float* KWh = (const float*)d_in[10];
    const float* Kbh = (const float*)d_in[11];
    const float* KWo = (const float*)d_in[12];
    const float* Kbo = (const float*)d_in[13];
    const float* VW0 = (const float*)d_in[14];
    const float* Vb0 = (const float*)d_in[15];
    const float* VWh = (const float*)d_in[16];
    const float* Vbh = (const float*)d_in[17];
    const float* VWo = (const float*)d_in[18];
    const float* Vbo = (const float*)d_in[19];

    float* ws = (float*)d_ws;
    const size_t BUF = (size_t)NXR * HD;       // 4,194,304 floats
    float* h1 = ws;
    float* h2 = ws + BUF;
    float* Qb = ws + 2 * BUF;
    float* Kb = ws + 3 * BUF;
    float* Vb = ws + 4 * BUF;                  // 8192*3 floats

    run_mlp(x, NXR, 3, QW0, Qb0, QWh, Qbh, QWo, Qbo, HD, h1, h2, Qb, stream);
    run_mlp(c, NCR, 3, KW0, Kb0, KWh, Kbh, KWo, Kbo, HD, h1, h2, Kb, stream);
    run_mlp(c, NCR, 3, VW0, Vb0, VWh, Vbh, VWo, Vbo, 3,  h1, h2, Vb, stream);

    hipMemsetAsync(d_out, 0, (size_t)out_size * sizeof(float), stream);

    dim3 ga(NXR / 64, 8);
    attn_fused<<<ga, dim3(256), 0, stream>>>(Qb, Kb, Vb, (float*)d_out, 8);
}

// Round 2
// 506.238 us; speedup vs baseline: 4.2524x; 4.2524x over previous
//
#include <hip/hip_runtime.h>
#include <math.h>

#define NXR 8192
#define NCR 8192
#define HD  512

typedef short s16x8 __attribute__((ext_vector_type(8)));
typedef float f32x4 __attribute__((ext_vector_type(4)));
typedef unsigned short u16;

__device__ inline u16 f2bf(float f) {
    unsigned int u = __float_as_uint(f);
    u = (u + 0x7FFFu + ((u >> 16) & 1u)) >> 16;
    return (u16)u;
}
__device__ inline float bf2f(u16 h) {
    return __uint_as_float(((unsigned int)h) << 16);
}

__device__ inline void async_load16(const void* g, void* l) {
    __builtin_amdgcn_global_load_lds(
        (const __attribute__((address_space(1))) unsigned int*)g,
        (__attribute__((address_space(3))) unsigned int*)l, 16, 0, 0);
}

// ---------------------------------------------------------------------------
// Weight transpose + bf16 convert: out[n][k] = (bf16)in[k][n], 512x512.
// ---------------------------------------------------------------------------
__global__ __launch_bounds__(256) void transpose_w(
    const float* __restrict__ in, u16* __restrict__ out)
{
    __shared__ float tile[32][33];
    int bx = blockIdx.x * 32, by = blockIdx.y * 32;
    int tx = threadIdx.x & 31, ty = threadIdx.x >> 5;  // ty 0..7
    for (int r = ty; r < 32; r += 8)
        tile[r][tx] = in[(size_t)(by + r) * HD + bx + tx];
    __syncthreads();
    for (int r = ty; r < 32; r += 8)
        out[(size_t)(bx + r) * HD + by + tx] = f2bf(tile[tx][r]);
}

// ---------------------------------------------------------------------------
// Layer 0: H[row][n] = bf16(sin(sum_{k<3} X[row][k]*W0[k][n] + b0[n]))
// ---------------------------------------------------------------------------
__global__ __launch_bounds__(256) void layer0(
    const float* __restrict__ X, const float* __restrict__ W0,
    const float* __restrict__ b0, u16* __restrict__ H)
{
    int idx = blockIdx.x * 256 + threadIdx.x;
    int n = idx & (HD - 1);
    int row = idx >> 9;
    float v = X[row * 3 + 0] * W0[n] + X[row * 3 + 1] * W0[HD + n] +
              X[row * 3 + 2] * W0[2 * HD + n] + b0[n];
    H[idx] = f2bf(__sinf(v));
}

// ---------------------------------------------------------------------------
// bf16 MFMA GEMM (m97 structure): C[m][n] = act(sum_k A[m][k]*Bt[n][k] + b[n])
// A: [8192][512] bf16, Bt: [512][512] bf16 (weights pre-transposed), C bf16.
// 128x128 tile / block, 4 waves each 64x64 (4x4 grid of 16x16x32 MFMAs),
// BK=32 with width-16 global_load_lds staging.
// ACT: 0 = identity, 1 = sin.
// ---------------------------------------------------------------------------
template<int ACT>
__global__ __launch_bounds__(256) void gemm_bt(
    const u16* __restrict__ A, const u16* __restrict__ Bt,
    const float* __restrict__ bias, u16* __restrict__ C)
{
    __shared__ u16 As[128 * 32];
    __shared__ u16 Bs[128 * 32];

    const int tid  = threadIdx.x;
    const int wave = tid >> 6;
    const int lane = tid & 63;
    const int wr = wave >> 1, wc = wave & 1;
    const int row0 = blockIdx.x * 128;
    const int col0 = blockIdx.y * 128;

    const int lr = lane >> 2;  // 0..15 (row within 16-row staging chunk)
    const int ls = lane & 3;   // 0..3  (16B segment within 64B row)
    const int qm = lane & 15;  // fragment row/col
    const int qk = (lane >> 4) * 8;

    f32x4 acc[4][4] = {};

    for (int kt = 0; kt < HD; kt += 32) {
        int r0 = wave * 32 + lr;
        async_load16(A  + (size_t)(row0 + r0)      * HD + kt + ls * 8, &As[r0 * 32 + ls * 8]);
        async_load16(A  + (size_t)(row0 + r0 + 16) * HD + kt + ls * 8, &As[(r0 + 16) * 32 + ls * 8]);
        async_load16(Bt + (size_t)(col0 + r0)      * HD + kt + ls * 8, &Bs[r0 * 32 + ls * 8]);
        async_load16(Bt + (size_t)(col0 + r0 + 16) * HD + kt + ls * 8, &Bs[(r0 + 16) * 32 + ls * 8]);
        __syncthreads();

        s16x8 af[4], bfr[4];
#pragma unroll
        for (int t = 0; t < 4; ++t)
            af[t]  = *(const s16x8*)&As[(wr * 64 + t * 16 + qm) * 32 + qk];
#pragma unroll
        for (int t = 0; t < 4; ++t)
            bfr[t] = *(const s16x8*)&Bs[(wc * 64 + t * 16 + qm) * 32 + qk];
#pragma unroll
        for (int i = 0; i < 4; ++i)
#pragma unroll
            for (int j = 0; j < 4; ++j)
                acc[i][j] = __builtin_amdgcn_mfma_f32_16x16x32_bf16(af[i], bfr[j], acc[i][j], 0, 0, 0);
        __syncthreads();
    }

    // C/D layout: col = lane&15, row = (lane>>4)*4 + reg  [verified m89/m91]
    const int cn = lane & 15;
    const int rq = lane >> 4;
#pragma unroll
    for (int i = 0; i < 4; ++i) {
#pragma unroll
        for (int j = 0; j < 4; ++j) {
            int gcol = col0 + wc * 64 + j * 16 + cn;
            float bv = bias[gcol];
#pragma unroll
            for (int r = 0; r < 4; ++r) {
                int grow = row0 + wr * 64 + i * 16 + rq * 4 + r;
                float v = acc[i][j][r] + bv;
                if (ACT) v = __sinf(v);
                C[(size_t)grow * HD + gcol] = f2bf(v);
            }
        }
    }
}

// ---------------------------------------------------------------------------
// V output layer (M=3): V[row][c] = sum_k H[row][k]*Wo[k][c] + bo[c], fp32 out.
// One wave per row.
// ---------------------------------------------------------------------------
__global__ __launch_bounds__(256) void vout_k(
    const u16* __restrict__ H, const float* __restrict__ Wo,
    const float* __restrict__ bo, float* __restrict__ V)
{
    int wave = threadIdx.x >> 6, lane = threadIdx.x & 63;
    int row = blockIdx.x * 4 + wave;
    s16x8 hv = *(const s16x8*)(H + (size_t)row * HD + lane * 8);
    float a0 = 0, a1 = 0, a2 = 0;
#pragma unroll
    for (int j = 0; j < 8; ++j) {
        float hf = bf2f(((const u16*)&hv)[j]);
        int k = lane * 8 + j;
        a0 += hf * Wo[k * 3 + 0];
        a1 += hf * Wo[k * 3 + 1];
        a2 += hf * Wo[k * 3 + 2];
    }
#pragma unroll
    for (int d = 32; d >= 1; d >>= 1) {
        a0 += __shfl_down(a0, d);
        a1 += __shfl_down(a1, d);
        a2 += __shfl_down(a2, d);
    }
    if (lane == 0) {
        V[row * 3 + 0] = a0 + bo[0];
        V[row * 3 + 1] = a1 + bo[1];
        V[row * 3 + 2] = a2 + bo[2];
    }
}

// ---------------------------------------------------------------------------
// Fused attention: out[i][c] += sum_j sigmoid(S[i][j]) * V[j][c]
// S-tile 128x128 via same MFMA structure; S never materialized.
// Grid (NX/128, NC/128); atomics accumulate across j-blocks (out pre-zeroed).
// ---------------------------------------------------------------------------
__global__ __launch_bounds__(256) void attn_mfma(
    const u16* __restrict__ Q, const u16* __restrict__ K,
    const float* __restrict__ V, float* __restrict__ out)
{
    __shared__ u16 Qs[128 * 32];
    __shared__ u16 Ks[128 * 32];
    __shared__ float Vs[128 * 3];

    const int tid = threadIdx.x;
    const int wave = tid >> 6, lane = tid & 63;
    const int wr = wave >> 1, wc = wave & 1;
    const int row0 = blockIdx.x * 128;
    const int col0 = blockIdx.y * 128;

    for (int t = tid; t < 384; t += 256) Vs[t] = V[(size_t)col0 * 3 + t];

    const int lr = lane >> 2, ls = lane & 3;
    const int qm = lane & 15, qk = (lane >> 4) * 8;

    f32x4 acc[4][4] = {};

    for (int kt = 0; kt < HD; kt += 32) {
        int r0 = wave * 32 + lr;
        async_load16(Q + (size_t)(row0 + r0)      * HD + kt + ls * 8, &Qs[r0 * 32 + ls * 8]);
        async_load16(Q + (size_t)(row0 + r0 + 16) * HD + kt + ls * 8, &Qs[(r0 + 16) * 32 + ls * 8]);
        async_load16(K + (size_t)(col0 + r0)      * HD + kt + ls * 8, &Ks[r0 * 32 + ls * 8]);
        async_load16(K + (size_t)(col0 + r0 + 16) * HD + kt + ls * 8, &Ks[(r0 + 16) * 32 + ls * 8]);
        __syncthreads();

        s16x8 af[4], bfr[4];
#pragma unroll
        for (int t = 0; t < 4; ++t)
            af[t]  = *(const s16x8*)&Qs[(wr * 64 + t * 16 + qm) * 32 + qk];
#pragma unroll
        for (int t = 0; t < 4; ++t)
            bfr[t] = *(const s16x8*)&Ks[(wc * 64 + t * 16 + qm) * 32 + qk];
#pragma unroll
        for (int i = 0; i < 4; ++i)
#pragma unroll
            for (int j = 0; j < 4; ++j)
                acc[i][j] = __builtin_amdgcn_mfma_f32_16x16x32_bf16(af[i], bfr[j], acc[i][j], 0, 0, 0);
        __syncthreads();
    }

    const int cn = lane & 15, rq = lane >> 4;
#pragma unroll
    for (int i = 0; i < 4; ++i) {
        float po[4][3] = {};
#pragma unroll
        for (int j = 0; j < 4; ++j) {
            int jj = wc * 64 + j * 16 + cn;
            float v0 = Vs[jj * 3 + 0], v1 = Vs[jj * 3 + 1], v2 = Vs[jj * 3 + 2];
#pragma unroll
            for (int r = 0; r < 4; ++r) {
                float s = 1.f / (1.f + __expf(-acc[i][j][r]));
                po[r][0] += s * v0;
                po[r][1] += s * v1;
                po[r][2] += s * v2;
            }
        }
#pragma unroll
        for (int r = 0; r < 4; ++r)
#pragma unroll
            for (int c = 0; c < 3; ++c) {
                float v = po[r][c];
                v += __shfl_down(v, 8, 16);
                v += __shfl_down(v, 4, 16);
                v += __shfl_down(v, 2, 16);
                v += __shfl_down(v, 1, 16);
                if (cn == 0)
                    atomicAdd(&out[(size_t)(row0 + wr * 64 + i * 16 + rq * 4 + r) * 3 + c], v);
            }
    }
}

// ---------------------------------------------------------------------------
extern "C" void kernel_launch(void* const* d_in, const int* in_sizes, int n_in,
                              void* d_out, int out_size, void* d_ws, size_t ws_size,
                              hipStream_t stream)
{
    const float* x   = (const float*)d_in[0];
    const float* c   = (const float*)d_in[1];
    const float* QW0 = (const float*)d_in[2];
    const float* Qb0 = (const float*)d_in[3];
    const float* QWh = (const float*)d_in[4];
    const float* Qbh = (const float*)d_in[5];
    const float* QWo = (const float*)d_in[6];
    const float* Qbo = (const float*)d_in[7];
    const float* KW0 = (const float*)d_in[8];
    const float* Kb0 = (const float*)d_in[9];
    const float* KWh = (const float*)d_in[10];
    const float* Kbh = (const float*)d_in[11];
    const float* KWo = (const float*)d_in[12];
    const float* Kbo = (const float*)d_in[13];
    const float* VW0 = (const float*)d_in[14];
    const float* Vb0 = (const float*)d_in[15];
    const float* VWh = (const float*)d_in[16];
    const float* Vbh = (const float*)d_in[17];
    const float* VWo = (const float*)d_in[18];
    const float* Vbo = (const float*)d_in[19];

    char* ws = (char*)d_ws;
    const size_t WTN = (size_t)HD * HD;     // 262144 elements per weight matrix
    u16*   wT = (u16*)ws;                   // 11 bf16 transposed weights (5.5 MiB)
    u16*   hA = (u16*)(ws + 6  * 1048576);  // 8192x512 bf16 (8 MiB)
    u16*   hB = (u16*)(ws + 14 * 1048576);
    u16*   Qb = (u16*)(ws + 22 * 1048576);
    u16*   Kb = (u16*)(ws + 30 * 1048576);
    float* Vf = (float*)(ws + 38 * 1048576); // 8192x3 fp32

    dim3 tb(256), tg(16, 16);
    for (int l = 0; l < 3; ++l)
        transpose_w<<<tg, tb, 0, stream>>>(QWh + l * WTN, wT + l * WTN);
    transpose_w<<<tg, tb, 0, stream>>>(QWo, wT + 3 * WTN);
    for (int l = 0; l < 3; ++l)
        transpose_w<<<tg, tb, 0, stream>>>(KWh + l * WTN, wT + (4 + l) * WTN);
    transpose_w<<<tg, tb, 0, stream>>>(KWo, wT + 7 * WTN);
    for (int l = 0; l < 3; ++l)
        transpose_w<<<tg, tb, 0, stream>>>(VWh + l * WTN, wT + (8 + l) * WTN);

    const int L0G = NXR * HD / 256;
    dim3 gb(256), gg(NXR / 128, HD / 128);  // (64, 4)

    // Q net
    layer0<<<L0G, 256, 0, stream>>>(x, QW0, Qb0, hA);
    gemm_bt<1><<<gg, gb, 0, stream>>>(hA, wT + 0 * WTN, Qbh + 0 * HD, hB);
    gemm_bt<1><<<gg, gb, 0, stream>>>(hB, wT + 1 * WTN, Qbh + 1 * HD, hA);
    gemm_bt<1><<<gg, gb, 0, stream>>>(hA, wT + 2 * WTN, Qbh + 2 * HD, hB);
    gemm_bt<0><<<gg, gb, 0, stream>>>(hB, wT + 3 * WTN, Qbo, Qb);
    // K net
    layer0<<<L0G, 256, 0, stream>>>(c, KW0, Kb0, hA);
    gemm_bt<1><<<gg, gb, 0, stream>>>(hA, wT + 4 * WTN, Kbh + 0 * HD, hB);
    gemm_bt<1><<<gg, gb, 0, stream>>>(hB, wT + 5 * WTN, Kbh + 1 * HD, hA);
    gemm_bt<1><<<gg, gb, 0, stream>>>(hA, wT + 6 * WTN, Kbh + 2 * HD, hB);
    gemm_bt<0><<<gg, gb, 0, stream>>>(hB, wT + 7 * WTN, Kbo, Kb);
    // V net
    layer0<<<L0G, 256, 0, stream>>>(c, VW0, Vb0, hA);
    gemm_bt<1><<<gg, gb, 0, stream>>>(hA, wT + 8 * WTN, Vbh + 0 * HD, hB);
    gemm_bt<1><<<gg, gb, 0, stream>>>(hB, wT + 9 * WTN, Vbh + 1 * HD, hA);
    gemm_bt<1><<<gg, gb, 0, stream>>>(hA, wT + 10 * WTN, Vbh + 2 * HD, hB);
    vout_k<<<NCR / 4, 256, 0, stream>>>(hB, VWo, Vbo, Vf);

    hipMemsetAsync(d_out, 0, (size_t)out_size * sizeof(float), stream);
    attn_mfma<<<dim3(NXR / 128, NCR / 128), 256, 0, stream>>>(Qb, Kb, Vf, (float*)d_out);
}

// Round 5
// 461.058 us; speedup vs baseline: 4.6691x; 1.0980x over previous
//
#include <hip/hip_runtime.h>
#include <math.h>

#define NXR 8192
#define NCR 8192
#define HD  512

typedef short s16x8 __attribute__((ext_vector_type(8)));
typedef float f32x4 __attribute__((ext_vector_type(4)));
typedef unsigned short u16;

struct P11 { const float* p[11]; };
struct P3  { const float* p[3]; };

__device__ inline u16 f2bf(float f) {
    unsigned int u = __float_as_uint(f);
    u = (u + 0x7FFFu + ((u >> 16) & 1u)) >> 16;
    return (u16)u;
}
__device__ inline float bf2f(u16 h) {
    return __uint_as_float(((unsigned int)h) << 16);
}

__device__ inline void async_load16(const void* g, void* l) {
    __builtin_amdgcn_global_load_lds(
        (const __attribute__((address_space(1))) unsigned int*)g,
        (__attribute__((address_space(3))) unsigned int*)l, 16, 0, 0);
}

// ---------------------------------------------------------------------------
// Fused weight transpose + bf16 convert: out[z][n][k] = (bf16)in_z[k][n].
// Layout: z = l*3+net for hidden layers, 9 = QWo, 10 = KWo. grid (16,16,11).
// ---------------------------------------------------------------------------
__global__ __launch_bounds__(256) void transpose_w_all(
    P11 srcs, u16* __restrict__ out)
{
    const float* in = srcs.p[blockIdx.z];
    u16* o = out + (size_t)blockIdx.z * HD * HD;
    __shared__ float tile[32][33];
    int bx = blockIdx.x * 32, by = blockIdx.y * 32;
    int tx = threadIdx.x & 31, ty = threadIdx.x >> 5;
    for (int r = ty; r < 32; r += 8)
        tile[r][tx] = in[(size_t)(by + r) * HD + bx + tx];
    __syncthreads();
    for (int r = ty; r < 32; r += 8)
        o[(size_t)(bx + r) * HD + by + tx] = f2bf(tile[tx][r]);
}

// ---------------------------------------------------------------------------
// Layer 0: H[z][row][n] = bf16(sin(sum_{k<3} X[row][k]*W0[k][n] + b0[n]))
// net = net_base + z selects x (net 0) vs c (nets 1,2). grid (16384,1,nz).
// ---------------------------------------------------------------------------
__global__ __launch_bounds__(256) void layer0_all(
    const float* __restrict__ x, const float* __restrict__ c,
    P3 W0p, P3 b0p, u16* __restrict__ H, int net_base)
{
    int z = blockIdx.z;
    int net = net_base + z;
    const float* X  = (net == 0) ? x : c;
    const float* W0 = W0p.p[z];
    const float* b0 = b0p.p[z];
    u16* Hn = H + (size_t)z * NXR * HD;

    int idx = blockIdx.x * 256 + threadIdx.x;
    int n = idx & (HD - 1);
    int row = idx >> 9;
    float v = X[row * 3 + 0] * W0[n] + X[row * 3 + 1] * W0[HD + n] +
              X[row * 3 + 2] * W0[2 * HD + n] + b0[n];
    Hn[idx] = f2bf(__sinf(v));
}

// ---------------------------------------------------------------------------
// Multi-net bf16 MFMA GEMM: z = net slot.
// C[z] = act(A[z] @ Bt[z]^T + bias[z]); A[z]=Abase+z*NXR*HD, Bt[z]=Wt0+z*wstride.
// 128x128 tile, 4 waves, 16x16x32 MFMA, BK=32, global_load_lds width 16.
// ---------------------------------------------------------------------------
template<int ACT>
__global__ __launch_bounds__(256) void gemm_bt_multi(
    const u16* __restrict__ Abase, const u16* __restrict__ Wt0, size_t wstride,
    P3 bias, u16* __restrict__ Cbase)
{
    __shared__ u16 As[128 * 32];
    __shared__ u16 Bs[128 * 32];

    const int net = blockIdx.z;
    const u16* A  = Abase + (size_t)net * NXR * HD;
    const u16* Bt = Wt0 + (size_t)net * wstride;
    const float* bias_p = bias.p[net];
    u16* C = Cbase + (size_t)net * NXR * HD;

    const int tid  = threadIdx.x;
    const int wave = tid >> 6;
    const int lane = tid & 63;
    const int wr = wave >> 1, wc = wave & 1;
    const int row0 = blockIdx.x * 128;
    const int col0 = blockIdx.y * 128;

    const int lr = lane >> 2;
    const int ls = lane & 3;
    const int qm = lane & 15;
    const int qk = (lane >> 4) * 8;

    f32x4 acc[4][4] = {};

    for (int kt = 0; kt < HD; kt += 32) {
        int r0 = wave * 32 + lr;
        async_load16(A  + (size_t)(row0 + r0)      * HD + kt + ls * 8, &As[r0 * 32 + ls * 8]);
        async_load16(A  + (size_t)(row0 + r0 + 16) * HD + kt + ls * 8, &As[(r0 + 16) * 32 + ls * 8]);
        async_load16(Bt + (size_t)(col0 + r0)      * HD + kt + ls * 8, &Bs[r0 * 32 + ls * 8]);
        async_load16(Bt + (size_t)(col0 + r0 + 16) * HD + kt + ls * 8, &Bs[(r0 + 16) * 32 + ls * 8]);
        __syncthreads();

        s16x8 af[4], bfr[4];
#pragma unroll
        for (int t = 0; t < 4; ++t)
            af[t]  = *(const s16x8*)&As[(wr * 64 + t * 16 + qm) * 32 + qk];
#pragma unroll
        for (int t = 0; t < 4; ++t)
            bfr[t] = *(const s16x8*)&Bs[(wc * 64 + t * 16 + qm) * 32 + qk];
#pragma unroll
        for (int i = 0; i < 4; ++i)
#pragma unroll
            for (int j = 0; j < 4; ++j)
                acc[i][j] = __builtin_amdgcn_mfma_f32_16x16x32_bf16(af[i], bfr[j], acc[i][j], 0, 0, 0);
        __syncthreads();
    }

    const int cn = lane & 15;
    const int rq = lane >> 4;
#pragma unroll
    for (int i = 0; i < 4; ++i) {
#pragma unroll
        for (int j = 0; j < 4; ++j) {
            int gcol = col0 + wc * 64 + j * 16 + cn;
            float bv = bias_p[gcol];
#pragma unroll
            for (int r = 0; r < 4; ++r) {
                int grow = row0 + wr * 64 + i * 16 + rq * 4 + r;
                float v = acc[i][j][r] + bv;
                if (ACT) v = __sinf(v);
                C[(size_t)grow * HD + gcol] = f2bf(v);
            }
        }
    }
}

// ---------------------------------------------------------------------------
// V output layer (M=3), one wave per row, fp32 out.
// ---------------------------------------------------------------------------
__global__ __launch_bounds__(256) void vout_k(
    const u16* __restrict__ H, const float* __restrict__ Wo,
    const float* __restrict__ bo, float* __restrict__ V)
{
    int wave = threadIdx.x >> 6, lane = threadIdx.x & 63;
    int row = blockIdx.x * 4 + wave;
    s16x8 hv = *(const s16x8*)(H + (size_t)row * HD + lane * 8);
    float a0 = 0, a1 = 0, a2 = 0;
#pragma unroll
    for (int j = 0; j < 8; ++j) {
        float hf = bf2f(((const u16*)&hv)[j]);
        int k = lane * 8 + j;
        a0 += hf * Wo[k * 3 + 0];
        a1 += hf * Wo[k * 3 + 1];
        a2 += hf * Wo[k * 3 + 2];
    }
#pragma unroll
    for (int d = 32; d >= 1; d >>= 1) {
        a0 += __shfl_down(a0, d);
        a1 += __shfl_down(a1, d);
        a2 += __shfl_down(a2, d);
    }
    if (lane == 0) {
        V[row * 3 + 0] = a0 + bo[0];
        V[row * 3 + 1] = a1 + bo[1];
        V[row * 3 + 2] = a2 + bo[2];
    }
}

// ---------------------------------------------------------------------------
// Fused attention: out[i][c] += sum_j sigmoid(S[i][j]) * V[j][c]
// grid (NX/128, 8). Each block processes JT=8 j-tiles of 128, keeping the
// per-row output partials in registers across tiles; one reduce+atomic at end.
// ---------------------------------------------------------------------------
#define JT 8
__global__ __launch_bounds__(256) void attn_mfma(
    const u16* __restrict__ Q, const u16* __restrict__ K,
    const float* __restrict__ V, float* __restrict__ out)
{
    __shared__ u16 Qs[128 * 32];
    __shared__ u16 Ks[128 * 32];
    __shared__ float Vs[128 * 3];

    const int tid = threadIdx.x;
    const int wave = tid >> 6, lane = tid & 63;
    const int wr = wave >> 1, wc = wave & 1;
    const int row0 = blockIdx.x * 128;

    const int lr = lane >> 2, ls = lane & 3;
    const int qm = lane & 15, qk = (lane >> 4) * 8;
    const int cn = lane & 15, rq = lane >> 4;

    float po[4][4][3] = {};   // [i][r][c], accumulated across all JT j-tiles

    for (int jt = 0; jt < JT; ++jt) {
        const int col0 = (blockIdx.y * JT + jt) * 128;

        f32x4 acc[4][4] = {};

        for (int kt = 0; kt < HD; kt += 32) {
            int r0 = wave * 32 + lr;
            async_load16(Q + (size_t)(row0 + r0)      * HD + kt + ls * 8, &Qs[r0 * 32 + ls * 8]);
            async_load16(Q + (size_t)(row0 + r0 + 16) * HD + kt + ls * 8, &Qs[(r0 + 16) * 32 + ls * 8]);
            async_load16(K + (size_t)(col0 + r0)      * HD + kt + ls * 8, &Ks[r0 * 32 + ls * 8]);
            async_load16(K + (size_t)(col0 + r0 + 16) * HD + kt + ls * 8, &Ks[(r0 + 16) * 32 + ls * 8]);
            __syncthreads();

            s16x8 af[4], bfr[4];
#pragma unroll
            for (int t = 0; t < 4; ++t)
                af[t]  = *(const s16x8*)&Qs[(wr * 64 + t * 16 + qm) * 32 + qk];
#pragma unroll
            for (int t = 0; t < 4; ++t)
                bfr[t] = *(const s16x8*)&Ks[(wc * 64 + t * 16 + qm) * 32 + qk];
#pragma unroll
            for (int i = 0; i < 4; ++i)
#pragma unroll
                for (int j = 0; j < 4; ++j)
                    acc[i][j] = __builtin_amdgcn_mfma_f32_16x16x32_bf16(af[i], bfr[j], acc[i][j], 0, 0, 0);
            __syncthreads();
        }

        // Load ALL 384 floats of the V tile (256 threads -> strided loop).
        // [R3/R4 bug: `if (tid < 384)` left Vs[256..383] uninitialized]
        for (int t = tid; t < 384; t += 256) Vs[t] = V[(size_t)col0 * 3 + t];
        __syncthreads();

#pragma unroll
        for (int i = 0; i < 4; ++i) {
#pragma unroll
            for (int j = 0; j < 4; ++j) {
                int jj = wc * 64 + j * 16 + cn;
                float v0 = Vs[jj * 3 + 0], v1 = Vs[jj * 3 + 1], v2 = Vs[jj * 3 + 2];
#pragma unroll
                for (int r = 0; r < 4; ++r) {
                    float s = 1.f / (1.f + __expf(-acc[i][j][r]));
                    po[i][r][0] += s * v0;
                    po[i][r][1] += s * v1;
                    po[i][r][2] += s * v2;
                }
            }
        }
        __syncthreads();
    }

#pragma unroll
    for (int i = 0; i < 4; ++i)
#pragma unroll
        for (int r = 0; r < 4; ++r)
#pragma unroll
            for (int c = 0; c < 3; ++c) {
                float v = po[i][r][c];
                v += __shfl_down(v, 8, 16);
                v += __shfl_down(v, 4, 16);
                v += __shfl_down(v, 2, 16);
                v += __shfl_down(v, 1, 16);
                if (cn == 0)
                    atomicAdd(&out[(size_t)(row0 + wr * 64 + i * 16 + rq * 4 + r) * 3 + c], v);
            }
}

// ---------------------------------------------------------------------------
// Workspace (peak 38.1 MB):
//   [0,  6) MB : wT — 11 transposed bf16 weights, slot l*3+net; 9=QWo, 10=KWo
//   [6, 22) MB : R1 — 16 MB activation region (2 nets x 8 MB)
//   [22,38) MB : R2 — 16 MB activation region
//   [38, 38.1) : Vf — 8192x3 fp32
// ---------------------------------------------------------------------------
extern "C" void kernel_launch(void* const* d_in, const int* in_sizes, int n_in,
                              void* d_out, int out_size, void* d_ws, size_t ws_size,
                              hipStream_t stream)
{
    const float* x   = (const float*)d_in[0];
    const float* c   = (const float*)d_in[1];
    const float* QW0 = (const float*)d_in[2];
    const float* Qb0 = (const float*)d_in[3];
    const float* QWh = (const float*)d_in[4];
    const float* Qbh = (const float*)d_in[5];
    const float* QWo = (const float*)d_in[6];
    const float* Qbo = (const float*)d_in[7];
    const float* KW0 = (const float*)d_in[8];
    const float* Kb0 = (const float*)d_in[9];
    const float* KWh = (const float*)d_in[10];
    const float* Kbh = (const float*)d_in[11];
    const float* KWo = (const float*)d_in[12];
    const float* Kbo = (const float*)d_in[13];
    const float* VW0 = (const float*)d_in[14];
    const float* Vb0 = (const float*)d_in[15];
    const float* VWh = (const float*)d_in[16];
    const float* Vbh = (const float*)d_in[17];
    const float* VWo = (const float*)d_in[18];
    const float* Vbo = (const float*)d_in[19];

    char* ws = (char*)d_ws;
    const size_t WTN = (size_t)HD * HD;
    const size_t MB = 1048576;
    u16*   wT = (u16*)ws;
    u16*   R1 = (u16*)(ws + 6 * MB);
    u16*   R2 = (u16*)(ws + 22 * MB);
    float* Vf = (float*)(ws + 38 * MB);

    // ---- weight transposes (1 dispatch) ----
    P11 tsrc;
    for (int l = 0; l < 3; ++l) {
        tsrc.p[l * 3 + 0] = QWh + (size_t)l * WTN;
        tsrc.p[l * 3 + 1] = KWh + (size_t)l * WTN;
        tsrc.p[l * 3 + 2] = VWh + (size_t)l * WTN;
    }
    tsrc.p[9]  = QWo;
    tsrc.p[10] = KWo;
    transpose_w_all<<<dim3(16, 16, 11), 256, 0, stream>>>(tsrc, wT);

    const int L0G = NXR * HD / 256;  // 16384

    // ---- phase V (z-extent 1, uses lower 8 MB of R1/R2) ----
    {
        P3 w0 = {{VW0, nullptr, nullptr}}, b0 = {{Vb0, nullptr, nullptr}};
        layer0_all<<<dim3(L0G, 1, 1), 256, 0, stream>>>(x, c, w0, b0, R1, 2);
    }
    dim3 gv(NXR / 128, HD / 128, 1);
    {
        P3 b = {{Vbh + 0 * HD, nullptr, nullptr}};
        gemm_bt_multi<1><<<gv, 256, 0, stream>>>(R1, wT + (0 * 3 + 2) * WTN, 0, b, R2);
    }
    {
        P3 b = {{Vbh + 1 * HD, nullptr, nullptr}};
        gemm_bt_multi<1><<<gv, 256, 0, stream>>>(R2, wT + (1 * 3 + 2) * WTN, 0, b, R1);
    }
    {
        P3 b = {{Vbh + 2 * HD, nullptr, nullptr}};
        gemm_bt_multi<1><<<gv, 256, 0, stream>>>(R1, wT + (2 * 3 + 2) * WTN, 0, b, R2);
    }
    vout_k<<<NCR / 4, 256, 0, stream>>>(R2, VWo, Vbo, Vf);

    // ---- phase QK (z-extent 2) ----
    {
        P3 w0 = {{QW0, KW0, nullptr}}, b0 = {{Qb0, Kb0, nullptr}};
        layer0_all<<<dim3(L0G, 1, 2), 256, 0, stream>>>(x, c, w0, b0, R1, 0);
    }
    dim3 gqk(NXR / 128, HD / 128, 2);
    {
        P3 b = {{Qbh + 0 * HD, Kbh + 0 * HD, nullptr}};
        gemm_bt_multi<1><<<gqk, 256, 0, stream>>>(R1, wT + 0 * 3 * WTN, WTN, b, R2);
    }
    {
        P3 b = {{Qbh + 1 * HD, Kbh + 1 * HD, nullptr}};
        gemm_bt_multi<1><<<gqk, 256, 0, stream>>>(R2, wT + 1 * 3 * WTN, WTN, b, R1);
    }
    {
        P3 b = {{Qbh + 2 * HD, Kbh + 2 * HD, nullptr}};
        gemm_bt_multi<1><<<gqk, 256, 0, stream>>>(R1, wT + 2 * 3 * WTN, WTN, b, R2);
    }
    {
        P3 b = {{Qbo, Kbo, nullptr}};
        gemm_bt_multi<0><<<gqk, 256, 0, stream>>>(R2, wT + 9 * WTN, WTN, b, R1);
    }

    // ---- attention ----
    hipMemsetAsync(d_out, 0, (size_t)out_size * sizeof(float), stream);
    attn_mfma<<<dim3(NXR / 128, NCR / 128 / JT), 256, 0, stream>>>(
        R1, R1 + (size_t)NXR * HD, Vf, (float*)d_out);
}

// Round 6
// 435.429 us; speedup vs baseline: 4.9439x; 1.0589x over previous
//
#include <hip/hip_runtime.h>
#include <math.h>

#define NXR 8192
#define NCR 8192
#define HD  512

typedef short s16x8 __attribute__((ext_vector_type(8)));
typedef float f32x4 __attribute__((ext_vector_type(4)));
typedef unsigned short u16;

struct P11 { const float* p[11]; };
struct P3  { const float* p[3]; };

__device__ inline u16 f2bf(float f) {
    unsigned int u = __float_as_uint(f);
    u = (u + 0x7FFFu + ((u >> 16) & 1u)) >> 16;
    return (u16)u;
}
__device__ inline float bf2f(u16 h) {
    return __uint_as_float(((unsigned int)h) << 16);
}

__device__ inline void async_load16(const void* g, void* l) {
    __builtin_amdgcn_global_load_lds(
        (const __attribute__((address_space(1))) unsigned int*)g,
        (__attribute__((address_space(3))) unsigned int*)l, 16, 0, 0);
}

// ---------------------------------------------------------------------------
// Fused weight transpose + bf16 convert: out[z][n][k] = (bf16)in_z[k][n].
// Layout: z = l*3+net for hidden layers, 9 = QWo, 10 = KWo. grid (16,16,11).
// ---------------------------------------------------------------------------
__global__ __launch_bounds__(256) void transpose_w_all(
    P11 srcs, u16* __restrict__ out)
{
    const float* in = srcs.p[blockIdx.z];
    u16* o = out + (size_t)blockIdx.z * HD * HD;
    __shared__ float tile[32][33];
    int bx = blockIdx.x * 32, by = blockIdx.y * 32;
    int tx = threadIdx.x & 31, ty = threadIdx.x >> 5;
    for (int r = ty; r < 32; r += 8)
        tile[r][tx] = in[(size_t)(by + r) * HD + bx + tx];
    __syncthreads();
    for (int r = ty; r < 32; r += 8)
        o[(size_t)(bx + r) * HD + by + tx] = f2bf(tile[tx][r]);
}

// ---------------------------------------------------------------------------
// Layer 0: H[z][row][n] = bf16(sin(sum_{k<3} X[row][k]*W0[k][n] + b0[n]))
// net = net_base + z selects x (net 0) vs c (nets 1,2). grid (16384,1,nz).
// ---------------------------------------------------------------------------
__global__ __launch_bounds__(256) void layer0_all(
    const float* __restrict__ x, const float* __restrict__ c,
    P3 W0p, P3 b0p, u16* __restrict__ H, int net_base)
{
    int z = blockIdx.z;
    int net = net_base + z;
    const float* X  = (net == 0) ? x : c;
    const float* W0 = W0p.p[z];
    const float* b0 = b0p.p[z];
    u16* Hn = H + (size_t)z * NXR * HD;

    int idx = blockIdx.x * 256 + threadIdx.x;
    int n = idx & (HD - 1);
    int row = idx >> 9;
    float v = X[row * 3 + 0] * W0[n] + X[row * 3 + 1] * W0[HD + n] +
              X[row * 3 + 2] * W0[2 * HD + n] + b0[n];
    Hn[idx] = f2bf(__sinf(v));
}

// ---------------------------------------------------------------------------
// Multi-net bf16 MFMA GEMM: z = net slot.
// C[z] = act(A[z] @ Bt[z]^T + bias[z]); A[z]=Abase+z*NXR*HD, Bt[z]=Wt0+z*wstride.
// 128x128 tile, 4 waves, 16x16x32 MFMA, BK=32, global_load_lds width 16.
// ---------------------------------------------------------------------------
template<int ACT>
__global__ __launch_bounds__(256) void gemm_bt_multi(
    const u16* __restrict__ Abase, const u16* __restrict__ Wt0, size_t wstride,
    P3 bias, u16* __restrict__ Cbase)
{
    __shared__ u16 As[128 * 32];
    __shared__ u16 Bs[128 * 32];

    const int net = blockIdx.z;
    const u16* A  = Abase + (size_t)net * NXR * HD;
    const u16* Bt = Wt0 + (size_t)net * wstride;
    const float* bias_p = bias.p[net];
    u16* C = Cbase + (size_t)net * NXR * HD;

    const int tid  = threadIdx.x;
    const int wave = tid >> 6;
    const int lane = tid & 63;
    const int wr = wave >> 1, wc = wave & 1;
    const int row0 = blockIdx.x * 128;
    const int col0 = blockIdx.y * 128;

    const int lr = lane >> 2;
    const int ls = lane & 3;
    const int qm = lane & 15;
    const int qk = (lane >> 4) * 8;

    f32x4 acc[4][4] = {};

    for (int kt = 0; kt < HD; kt += 32) {
        int r0 = wave * 32 + lr;
        async_load16(A  + (size_t)(row0 + r0)      * HD + kt + ls * 8, &As[r0 * 32 + ls * 8]);
        async_load16(A  + (size_t)(row0 + r0 + 16) * HD + kt + ls * 8, &As[(r0 + 16) * 32 + ls * 8]);
        async_load16(Bt + (size_t)(col0 + r0)      * HD + kt + ls * 8, &Bs[r0 * 32 + ls * 8]);
        async_load16(Bt + (size_t)(col0 + r0 + 16) * HD + kt + ls * 8, &Bs[(r0 + 16) * 32 + ls * 8]);
        __syncthreads();

        s16x8 af[4], bfr[4];
#pragma unroll
        for (int t = 0; t < 4; ++t)
            af[t]  = *(const s16x8*)&As[(wr * 64 + t * 16 + qm) * 32 + qk];
#pragma unroll
        for (int t = 0; t < 4; ++t)
            bfr[t] = *(const s16x8*)&Bs[(wc * 64 + t * 16 + qm) * 32 + qk];
#pragma unroll
        for (int i = 0; i < 4; ++i)
#pragma unroll
            for (int j = 0; j < 4; ++j)
                acc[i][j] = __builtin_amdgcn_mfma_f32_16x16x32_bf16(af[i], bfr[j], acc[i][j], 0, 0, 0);
        __syncthreads();
    }

    const int cn = lane & 15;
    const int rq = lane >> 4;
#pragma unroll
    for (int i = 0; i < 4; ++i) {
#pragma unroll
        for (int j = 0; j < 4; ++j) {
            int gcol = col0 + wc * 64 + j * 16 + cn;
            float bv = bias_p[gcol];
#pragma unroll
            for (int r = 0; r < 4; ++r) {
                int grow = row0 + wr * 64 + i * 16 + rq * 4 + r;
                float v = acc[i][j][r] + bv;
                if (ACT) v = __sinf(v);
                C[(size_t)grow * HD + gcol] = f2bf(v);
            }
        }
    }
}

// ---------------------------------------------------------------------------
// V output layer (M=3), one wave per row, fp32 out.
// ---------------------------------------------------------------------------
__global__ __launch_bounds__(256) void vout_k(
    const u16* __restrict__ H, const float* __restrict__ Wo,
    const float* __restrict__ bo, float* __restrict__ V)
{
    int wave = threadIdx.x >> 6, lane = threadIdx.x & 63;
    int row = blockIdx.x * 4 + wave;
    s16x8 hv = *(const s16x8*)(H + (size_t)row * HD + lane * 8);
    float a0 = 0, a1 = 0, a2 = 0;
#pragma unroll
    for (int j = 0; j < 8; ++j) {
        float hf = bf2f(((const u16*)&hv)[j]);
        int k = lane * 8 + j;
        a0 += hf * Wo[k * 3 + 0];
        a1 += hf * Wo[k * 3 + 1];
        a2 += hf * Wo[k * 3 + 2];
    }
#pragma unroll
    for (int d = 32; d >= 1; d >>= 1) {
        a0 += __shfl_down(a0, d);
        a1 += __shfl_down(a1, d);
        a2 += __shfl_down(a2, d);
    }
    if (lane == 0) {
        V[row * 3 + 0] = a0 + bo[0];
        V[row * 3 + 1] = a1 + bo[1];
        V[row * 3 + 2] = a2 + bo[2];
    }
}

// ---------------------------------------------------------------------------
// Fused attention: out[i][c] += sum_j sigmoid(S[i][j]) * V[j][c]
// grid (NX/128, NC/128/JT). JT=4 j-tiles per block; V read directly from
// global (L2-hot, 96 KB) — no Vs staging barriers. One reduce+atomic at end.
// ---------------------------------------------------------------------------
#define JT 4
__global__ __launch_bounds__(256, 3) void attn_mfma(
    const u16* __restrict__ Q, const u16* __restrict__ K,
    const float* __restrict__ V, float* __restrict__ out)
{
    __shared__ u16 Qs[128 * 32];
    __shared__ u16 Ks[128 * 32];

    const int tid = threadIdx.x;
    const int wave = tid >> 6, lane = tid & 63;
    const int wr = wave >> 1, wc = wave & 1;
    const int row0 = blockIdx.x * 128;

    const int lr = lane >> 2, ls = lane & 3;
    const int qm = lane & 15, qk = (lane >> 4) * 8;
    const int cn = lane & 15, rq = lane >> 4;

    float po[4][4][3] = {};   // [i][r][c], accumulated across all JT j-tiles

    for (int jt = 0; jt < JT; ++jt) {
        const int col0 = (blockIdx.y * JT + jt) * 128;

        f32x4 acc[4][4] = {};

        for (int kt = 0; kt < HD; kt += 32) {
            int r0 = wave * 32 + lr;
            async_load16(Q + (size_t)(row0 + r0)      * HD + kt + ls * 8, &Qs[r0 * 32 + ls * 8]);
            async_load16(Q + (size_t)(row0 + r0 + 16) * HD + kt + ls * 8, &Qs[(r0 + 16) * 32 + ls * 8]);
            async_load16(K + (size_t)(col0 + r0)      * HD + kt + ls * 8, &Ks[r0 * 32 + ls * 8]);
            async_load16(K + (size_t)(col0 + r0 + 16) * HD + kt + ls * 8, &Ks[(r0 + 16) * 32 + ls * 8]);
            __syncthreads();

            s16x8 af[4], bfr[4];
#pragma unroll
            for (int t = 0; t < 4; ++t)
                af[t]  = *(const s16x8*)&Qs[(wr * 64 + t * 16 + qm) * 32 + qk];
#pragma unroll
            for (int t = 0; t < 4; ++t)
                bfr[t] = *(const s16x8*)&Ks[(wc * 64 + t * 16 + qm) * 32 + qk];
#pragma unroll
            for (int i = 0; i < 4; ++i)
#pragma unroll
                for (int j = 0; j < 4; ++j)
                    acc[i][j] = __builtin_amdgcn_mfma_f32_16x16x32_bf16(af[i], bfr[j], acc[i][j], 0, 0, 0);
            __syncthreads();
        }

        // sigmoid + PV; V rows read straight from global (L2-resident).
#pragma unroll
        for (int j = 0; j < 4; ++j) {
            size_t jj = (size_t)(col0 + wc * 64 + j * 16 + cn) * 3;
            float v0 = V[jj + 0], v1 = V[jj + 1], v2 = V[jj + 2];
#pragma unroll
            for (int i = 0; i < 4; ++i)
#pragma unroll
                for (int r = 0; r < 4; ++r) {
                    float s = 1.f / (1.f + __expf(-acc[i][j][r]));
                    po[i][r][0] += s * v0;
                    po[i][r][1] += s * v1;
                    po[i][r][2] += s * v2;
                }
        }
    }

#pragma unroll
    for (int i = 0; i < 4; ++i)
#pragma unroll
        for (int r = 0; r < 4; ++r)
#pragma unroll
            for (int c = 0; c < 3; ++c) {
                float v = po[i][r][c];
                v += __shfl_down(v, 8, 16);
                v += __shfl_down(v, 4, 16);
                v += __shfl_down(v, 2, 16);
                v += __shfl_down(v, 1, 16);
                if (cn == 0)
                    atomicAdd(&out[(size_t)(row0 + wr * 64 + i * 16 + rq * 4 + r) * 3 + c], v);
            }
}

// ---------------------------------------------------------------------------
// Workspace layouts:
//  FUSED (needs >=57 MB):  [0,6) wT | [6,30) hA (3 nets) | [30,54) hB | [54,..) Vf
//  FALLBACK (38.1 MB):     [0,6) wT | [6,22) R1 (2 nets) | [22,38) R2 | [38,..) Vf
// ws_size is launch-invariant, so branching on it is graph-capture-safe.
// ---------------------------------------------------------------------------
extern "C" void kernel_launch(void* const* d_in, const int* in_sizes, int n_in,
                              void* d_out, int out_size, void* d_ws, size_t ws_size,
                              hipStream_t stream)
{
    const float* x   = (const float*)d_in[0];
    const float* c   = (const float*)d_in[1];
    const float* QW0 = (const float*)d_in[2];
    const float* Qb0 = (const float*)d_in[3];
    const float* QWh = (const float*)d_in[4];
    const float* Qbh = (const float*)d_in[5];
    const float* QWo = (const float*)d_in[6];
    const float* Qbo = (const float*)d_in[7];
    const float* KW0 = (const float*)d_in[8];
    const float* Kb0 = (const float*)d_in[9];
    const float* KWh = (const float*)d_in[10];
    const float* Kbh = (const float*)d_in[11];
    const float* KWo = (const float*)d_in[12];
    const float* Kbo = (const float*)d_in[13];
    const float* VW0 = (const float*)d_in[14];
    const float* Vb0 = (const float*)d_in[15];
    const float* VWh = (const float*)d_in[16];
    const float* Vbh = (const float*)d_in[17];
    const float* VWo = (const float*)d_in[18];
    const float* Vbo = (const float*)d_in[19];

    char* ws = (char*)d_ws;
    const size_t WTN = (size_t)HD * HD;
    const size_t MB = 1048576;
    const size_t NET = (size_t)NXR * HD;

    // ---- weight transposes (1 dispatch, both paths) ----
    u16* wT = (u16*)ws;
    P11 tsrc;
    for (int l = 0; l < 3; ++l) {
        tsrc.p[l * 3 + 0] = QWh + (size_t)l * WTN;
        tsrc.p[l * 3 + 1] = KWh + (size_t)l * WTN;
        tsrc.p[l * 3 + 2] = VWh + (size_t)l * WTN;
    }
    tsrc.p[9]  = QWo;
    tsrc.p[10] = KWo;
    transpose_w_all<<<dim3(16, 16, 11), 256, 0, stream>>>(tsrc, wT);

    const int L0G = NXR * HD / 256;  // 16384
    const u16* Qb; const u16* Kb; const float* Vf;

    if (ws_size >= 57 * MB) {
        // ================= fused path =================
        u16*   hA = (u16*)(ws + 6 * MB);
        u16*   hB = (u16*)(ws + 30 * MB);
        float* Vff = (float*)(ws + 54 * MB);

        P3 w0 = {{QW0, KW0, VW0}}, b0 = {{Qb0, Kb0, Vb0}};
        layer0_all<<<dim3(L0G, 1, 3), 256, 0, stream>>>(x, c, w0, b0, hA, 0);

        dim3 g3(NXR / 128, HD / 128, 3);
        {
            P3 b = {{Qbh + 0 * HD, Kbh + 0 * HD, Vbh + 0 * HD}};
            gemm_bt_multi<1><<<g3, 256, 0, stream>>>(hA, wT + 0 * 3 * WTN, WTN, b, hB);
        }
        {
            P3 b = {{Qbh + 1 * HD, Kbh + 1 * HD, Vbh + 1 * HD}};
            gemm_bt_multi<1><<<g3, 256, 0, stream>>>(hB, wT + 1 * 3 * WTN, WTN, b, hA);
        }
        {
            P3 b = {{Qbh + 2 * HD, Kbh + 2 * HD, Vbh + 2 * HD}};
            gemm_bt_multi<1><<<g3, 256, 0, stream>>>(hA, wT + 2 * 3 * WTN, WTN, b, hB);
        }
        {
            P3 b = {{Qbo, Kbo, nullptr}};
            gemm_bt_multi<0><<<dim3(NXR / 128, HD / 128, 2), 256, 0, stream>>>(
                hB, wT + 9 * WTN, WTN, b, hA);
        }
        vout_k<<<NCR / 4, 256, 0, stream>>>(hB + 2 * NET, VWo, Vbo, Vff);

        Qb = hA; Kb = hA + NET; Vf = Vff;
    } else {
        // ================= two-phase fallback (proven 38.1 MB) =================
        u16*   R1 = (u16*)(ws + 6 * MB);
        u16*   R2 = (u16*)(ws + 22 * MB);
        float* Vff = (float*)(ws + 38 * MB);

        {
            P3 w0 = {{VW0, nullptr, nullptr}}, b0 = {{Vb0, nullptr, nullptr}};
            layer0_all<<<dim3(L0G, 1, 1), 256, 0, stream>>>(x, c, w0, b0, R1, 2);
        }
        dim3 gv(NXR / 128, HD / 128, 1);
        {
            P3 b = {{Vbh + 0 * HD, nullptr, nullptr}};
            gemm_bt_multi<1><<<gv, 256, 0, stream>>>(R1, wT + (0 * 3 + 2) * WTN, 0, b, R2);
        }
        {
            P3 b = {{Vbh + 1 * HD, nullptr, nullptr}};
            gemm_bt_multi<1><<<gv, 256, 0, stream>>>(R2, wT + (1 * 3 + 2) * WTN, 0, b, R1);
        }
        {
            P3 b = {{Vbh + 2 * HD, nullptr, nullptr}};
            gemm_bt_multi<1><<<gv, 256, 0, stream>>>(R1, wT + (2 * 3 + 2) * WTN, 0, b, R2);
        }
        vout_k<<<NCR / 4, 256, 0, stream>>>(R2, VWo, Vbo, Vff);

        {
            P3 w0 = {{QW0, KW0, nullptr}}, b0 = {{Qb0, Kb0, nullptr}};
            layer0_all<<<dim3(L0G, 1, 2), 256, 0, stream>>>(x, c, w0, b0, R1, 0);
        }
        dim3 gqk(NXR / 128, HD / 128, 2);
        {
            P3 b = {{Qbh + 0 * HD, Kbh + 0 * HD, nullptr}};
            gemm_bt_multi<1><<<gqk, 256, 0, stream>>>(R1, wT + 0 * 3 * WTN, WTN, b, R2);
        }
        {
            P3 b = {{Qbh + 1 * HD, Kbh + 1 * HD, nullptr}};
            gemm_bt_multi<1><<<gqk, 256, 0, stream>>>(R2, wT + 1 * 3 * WTN, WTN, b, R1);
        }
        {
            P3 b = {{Qbh + 2 * HD, Kbh + 2 * HD, nullptr}};
            gemm_bt_multi<1><<<gqk, 256, 0, stream>>>(R1, wT + 2 * 3 * WTN, WTN, b, R2);
        }
        {
            P3 b = {{Qbo, Kbo, nullptr}};
            gemm_bt_multi<0><<<gqk, 256, 0, stream>>>(R2, wT + 9 * WTN, WTN, b, R1);
        }
        Qb = R1; Kb = R1 + NET; Vf = Vff;
    }

    // ---- attention ----
    hipMemsetAsync(d_out, 0, (size_t)out_size * sizeof(float), stream);
    attn_mfma<<<dim3(NXR / 128, NCR / 128 / JT), 256, 0, stream>>>(
        Qb, Kb, Vf, (float*)d_out);
}

// Round 7
// 415.889 us; speedup vs baseline: 5.1762x; 1.0470x over previous
//
#include <hip/hip_runtime.h>
#include <math.h>

#define NXR 8192
#define NCR 8192
#define HD  512

typedef short s16x8 __attribute__((ext_vector_type(8)));
typedef float f32x4 __attribute__((ext_vector_type(4)));
typedef unsigned short u16;

struct P11 { const float* p[11]; };
struct P3  { const float* p[3]; };

__device__ inline u16 f2bf(float f) {
    unsigned int u = __float_as_uint(f);
    u = (u + 0x7FFFu + ((u >> 16) & 1u)) >> 16;
    return (u16)u;
}
__device__ inline float bf2f(u16 h) {
    return __uint_as_float(((unsigned int)h) << 16);
}

__device__ inline void async_load16(const void* g, void* l) {
    __builtin_amdgcn_global_load_lds(
        (const __attribute__((address_space(1))) unsigned int*)g,
        (__attribute__((address_space(3))) unsigned int*)l, 16, 0, 0);
}

// ---------------------------------------------------------------------------
// Fused weight transpose + bf16 convert: out[z][n][k] = (bf16)in_z[k][n].
// Layout: z = l*3+net for hidden layers, 9 = QWo, 10 = KWo. grid (16,16,11).
// ---------------------------------------------------------------------------
__global__ __launch_bounds__(256) void transpose_w_all(
    P11 srcs, u16* __restrict__ out)
{
    const float* in = srcs.p[blockIdx.z];
    u16* o = out + (size_t)blockIdx.z * HD * HD;
    __shared__ float tile[32][33];
    int bx = blockIdx.x * 32, by = blockIdx.y * 32;
    int tx = threadIdx.x & 31, ty = threadIdx.x >> 5;
    for (int r = ty; r < 32; r += 8)
        tile[r][tx] = in[(size_t)(by + r) * HD + bx + tx];
    __syncthreads();
    for (int r = ty; r < 32; r += 8)
        o[(size_t)(bx + r) * HD + by + tx] = f2bf(tile[tx][r]);
}

// ---------------------------------------------------------------------------
// Layer 0: H[z][row][n] = bf16(sin(sum_{k<3} X[row][k]*W0[k][n] + b0[n]))
// net = net_base + z selects x (net 0) vs c (nets 1,2). grid (16384,1,nz).
// ---------------------------------------------------------------------------
__global__ __launch_bounds__(256) void layer0_all(
    const float* __restrict__ x, const float* __restrict__ c,
    P3 W0p, P3 b0p, u16* __restrict__ H, int net_base)
{
    int z = blockIdx.z;
    int net = net_base + z;
    const float* X  = (net == 0) ? x : c;
    const float* W0 = W0p.p[z];
    const float* b0 = b0p.p[z];
    u16* Hn = H + (size_t)z * NXR * HD;

    int idx = blockIdx.x * 256 + threadIdx.x;
    int n = idx & (HD - 1);
    int row = idx >> 9;
    float v = X[row * 3 + 0] * W0[n] + X[row * 3 + 1] * W0[HD + n] +
              X[row * 3 + 2] * W0[2 * HD + n] + b0[n];
    Hn[idx] = f2bf(__sinf(v));
}

// ---------------------------------------------------------------------------
// Multi-net bf16 MFMA GEMM: z = net slot.
// C[z] = act(A[z] @ Bt[z]^T + bias[z]); A[z]=Abase+z*NXR*HD, Bt[z]=Wt0+z*wstride.
// 128x128 tile, 4 waves, 16x16x32 MFMA, BK=32, global_load_lds width 16.
// ---------------------------------------------------------------------------
template<int ACT>
__global__ __launch_bounds__(256) void gemm_bt_multi(
    const u16* __restrict__ Abase, const u16* __restrict__ Wt0, size_t wstride,
    P3 bias, u16* __restrict__ Cbase)
{
    __shared__ u16 As[128 * 32];
    __shared__ u16 Bs[128 * 32];

    const int net = blockIdx.z;
    const u16* A  = Abase + (size_t)net * NXR * HD;
    const u16* Bt = Wt0 + (size_t)net * wstride;
    const float* bias_p = bias.p[net];
    u16* C = Cbase + (size_t)net * NXR * HD;

    const int tid  = threadIdx.x;
    const int wave = tid >> 6;
    const int lane = tid & 63;
    const int wr = wave >> 1, wc = wave & 1;
    const int row0 = blockIdx.x * 128;
    const int col0 = blockIdx.y * 128;

    const int lr = lane >> 2;
    const int ls = lane & 3;
    const int qm = lane & 15;
    const int qk = (lane >> 4) * 8;

    f32x4 acc[4][4] = {};

    for (int kt = 0; kt < HD; kt += 32) {
        int r0 = wave * 32 + lr;
        async_load16(A  + (size_t)(row0 + r0)      * HD + kt + ls * 8, &As[r0 * 32 + ls * 8]);
        async_load16(A  + (size_t)(row0 + r0 + 16) * HD + kt + ls * 8, &As[(r0 + 16) * 32 + ls * 8]);
        async_load16(Bt + (size_t)(col0 + r0)      * HD + kt + ls * 8, &Bs[r0 * 32 + ls * 8]);
        async_load16(Bt + (size_t)(col0 + r0 + 16) * HD + kt + ls * 8, &Bs[(r0 + 16) * 32 + ls * 8]);
        __syncthreads();

        s16x8 af[4], bfr[4];
#pragma unroll
        for (int t = 0; t < 4; ++t)
            af[t]  = *(const s16x8*)&As[(wr * 64 + t * 16 + qm) * 32 + qk];
#pragma unroll
        for (int t = 0; t < 4; ++t)
            bfr[t] = *(const s16x8*)&Bs[(wc * 64 + t * 16 + qm) * 32 + qk];
#pragma unroll
        for (int i = 0; i < 4; ++i)
#pragma unroll
            for (int j = 0; j < 4; ++j)
                acc[i][j] = __builtin_amdgcn_mfma_f32_16x16x32_bf16(af[i], bfr[j], acc[i][j], 0, 0, 0);
        __syncthreads();
    }

    const int cn = lane & 15;
    const int rq = lane >> 4;
#pragma unroll
    for (int i = 0; i < 4; ++i) {
#pragma unroll
        for (int j = 0; j < 4; ++j) {
            int gcol = col0 + wc * 64 + j * 16 + cn;
            float bv = bias_p[gcol];
#pragma unroll
            for (int r = 0; r < 4; ++r) {
                int grow = row0 + wr * 64 + i * 16 + rq * 4 + r;
                float v = acc[i][j][r] + bv;
                if (ACT) v = __sinf(v);
                C[(size_t)grow * HD + gcol] = f2bf(v);
            }
        }
    }
}

// ---------------------------------------------------------------------------
// V output layer (M=3), one wave per row, fp32 out.
// ---------------------------------------------------------------------------
__global__ __launch_bounds__(256) void vout_k(
    const u16* __restrict__ H, const float* __restrict__ Wo,
    const float* __restrict__ bo, float* __restrict__ V)
{
    int wave = threadIdx.x >> 6, lane = threadIdx.x & 63;
    int row = blockIdx.x * 4 + wave;
    s16x8 hv = *(const s16x8*)(H + (size_t)row * HD + lane * 8);
    float a0 = 0, a1 = 0, a2 = 0;
#pragma unroll
    for (int j = 0; j < 8; ++j) {
        float hf = bf2f(((const u16*)&hv)[j]);
        int k = lane * 8 + j;
        a0 += hf * Wo[k * 3 + 0];
        a1 += hf * Wo[k * 3 + 1];
        a2 += hf * Wo[k * 3 + 2];
    }
#pragma unroll
    for (int d = 32; d >= 1; d >>= 1) {
        a0 += __shfl_down(a0, d);
        a1 += __shfl_down(a1, d);
        a2 += __shfl_down(a2, d);
    }
    if (lane == 0) {
        V[row * 3 + 0] = a0 + bo[0];
        V[row * 3 + 1] = a1 + bo[1];
        V[row * 3 + 2] = a2 + bo[2];
    }
}

// ---------------------------------------------------------------------------
// Fused attention: out[i][c] += sum_j sigmoid(S[i][j]) * V[j][c]
// grid (NX/128, NC/128/JT), JT=4. Natural register allocation (NO min-waves
// bound: R6's (256,3) forced VGPR 152->84 and spilled 139 MB/dispatch).
// V preloaded into registers before each j-tile's K-loop (hides L2 latency).
// Sigmoid via 1-ulp v_rcp_f32 instead of exact-IEEE division.
// ---------------------------------------------------------------------------
#define JT 4
__global__ __launch_bounds__(256) void attn_mfma(
    const u16* __restrict__ Q, const u16* __restrict__ K,
    const float* __restrict__ V, float* __restrict__ out)
{
    __shared__ u16 Qs[128 * 32];
    __shared__ u16 Ks[128 * 32];

    const int tid = threadIdx.x;
    const int wave = tid >> 6, lane = tid & 63;
    const int wr = wave >> 1, wc = wave & 1;
    const int row0 = blockIdx.x * 128;

    const int lr = lane >> 2, ls = lane & 3;
    const int qm = lane & 15, qk = (lane >> 4) * 8;
    const int cn = lane & 15, rq = lane >> 4;

    float po[4][4][3] = {};   // [i][r][c], accumulated across all JT j-tiles

    for (int jt = 0; jt < JT; ++jt) {
        const int col0 = (blockIdx.y * JT + jt) * 128;

        // Preload this j-tile's V rows into registers (latency hidden by K-loop).
        float vv[4][3];
#pragma unroll
        for (int j = 0; j < 4; ++j) {
            size_t jj = (size_t)(col0 + wc * 64 + j * 16 + cn) * 3;
            vv[j][0] = V[jj + 0];
            vv[j][1] = V[jj + 1];
            vv[j][2] = V[jj + 2];
        }

        f32x4 acc[4][4] = {};

        for (int kt = 0; kt < HD; kt += 32) {
            int r0 = wave * 32 + lr;
            async_load16(Q + (size_t)(row0 + r0)      * HD + kt + ls * 8, &Qs[r0 * 32 + ls * 8]);
            async_load16(Q + (size_t)(row0 + r0 + 16) * HD + kt + ls * 8, &Qs[(r0 + 16) * 32 + ls * 8]);
            async_load16(K + (size_t)(col0 + r0)      * HD + kt + ls * 8, &Ks[r0 * 32 + ls * 8]);
            async_load16(K + (size_t)(col0 + r0 + 16) * HD + kt + ls * 8, &Ks[(r0 + 16) * 32 + ls * 8]);
            __syncthreads();

            s16x8 af[4], bfr[4];
#pragma unroll
            for (int t = 0; t < 4; ++t)
                af[t]  = *(const s16x8*)&Qs[(wr * 64 + t * 16 + qm) * 32 + qk];
#pragma unroll
            for (int t = 0; t < 4; ++t)
                bfr[t] = *(const s16x8*)&Ks[(wc * 64 + t * 16 + qm) * 32 + qk];
#pragma unroll
            for (int i = 0; i < 4; ++i)
#pragma unroll
                for (int j = 0; j < 4; ++j)
                    acc[i][j] = __builtin_amdgcn_mfma_f32_16x16x32_bf16(af[i], bfr[j], acc[i][j], 0, 0, 0);
            __syncthreads();
        }

        // sigmoid + PV accumulate (rcp = v_rcp_f32, 1 ulp)
#pragma unroll
        for (int j = 0; j < 4; ++j) {
            float v0 = vv[j][0], v1 = vv[j][1], v2 = vv[j][2];
#pragma unroll
            for (int i = 0; i < 4; ++i)
#pragma unroll
                for (int r = 0; r < 4; ++r) {
                    float s = __builtin_amdgcn_rcpf(1.f + __expf(-acc[i][j][r]));
                    po[i][r][0] += s * v0;
                    po[i][r][1] += s * v1;
                    po[i][r][2] += s * v2;
                }
        }
    }

#pragma unroll
    for (int i = 0; i < 4; ++i)
#pragma unroll
        for (int r = 0; r < 4; ++r)
#pragma unroll
            for (int c = 0; c < 3; ++c) {
                float v = po[i][r][c];
                v += __shfl_down(v, 8, 16);
                v += __shfl_down(v, 4, 16);
                v += __shfl_down(v, 2, 16);
                v += __shfl_down(v, 1, 16);
                if (cn == 0)
                    atomicAdd(&out[(size_t)(row0 + wr * 64 + i * 16 + rq * 4 + r) * 3 + c], v);
            }
}

// ---------------------------------------------------------------------------
// Workspace layouts:
//  FUSED (needs >=57 MB):  [0,6) wT | [6,30) hA (3 nets) | [30,54) hB | [54,..) Vf
//  FALLBACK (38.1 MB):     [0,6) wT | [6,22) R1 (2 nets) | [22,38) R2 | [38,..) Vf
// ws_size is launch-invariant, so branching on it is graph-capture-safe.
// ---------------------------------------------------------------------------
extern "C" void kernel_launch(void* const* d_in, const int* in_sizes, int n_in,
                              void* d_out, int out_size, void* d_ws, size_t ws_size,
                              hipStream_t stream)
{
    const float* x   = (const float*)d_in[0];
    const float* c   = (const float*)d_in[1];
    const float* QW0 = (const float*)d_in[2];
    const float* Qb0 = (const float*)d_in[3];
    const float* QWh = (const float*)d_in[4];
    const float* Qbh = (const float*)d_in[5];
    const float* QWo = (const float*)d_in[6];
    const float* Qbo = (const float*)d_in[7];
    const float* KW0 = (const float*)d_in[8];
    const float* Kb0 = (const float*)d_in[9];
    const float* KWh = (const float*)d_in[10];
    const float* Kbh = (const float*)d_in[11];
    const float* KWo = (const float*)d_in[12];
    const float* Kbo = (const float*)d_in[13];
    const float* VW0 = (const float*)d_in[14];
    const float* Vb0 = (const float*)d_in[15];
    const float* VWh = (const float*)d_in[16];
    const float* Vbh = (const float*)d_in[17];
    const float* VWo = (const float*)d_in[18];
    const float* Vbo = (const float*)d_in[19];

    char* ws = (char*)d_ws;
    const size_t WTN = (size_t)HD * HD;
    const size_t MB = 1048576;
    const size_t NET = (size_t)NXR * HD;

    // ---- weight transposes (1 dispatch, both paths) ----
    u16* wT = (u16*)ws;
    P11 tsrc;
    for (int l = 0; l < 3; ++l) {
        tsrc.p[l * 3 + 0] = QWh + (size_t)l * WTN;
        tsrc.p[l * 3 + 1] = KWh + (size_t)l * WTN;
        tsrc.p[l * 3 + 2] = VWh + (size_t)l * WTN;
    }
    tsrc.p[9]  = QWo;
    tsrc.p[10] = KWo;
    transpose_w_all<<<dim3(16, 16, 11), 256, 0, stream>>>(tsrc, wT);

    const int L0G = NXR * HD / 256;  // 16384
    const u16* Qb; const u16* Kb; const float* Vf;

    if (ws_size >= 57 * MB) {
        // ================= fused path =================
        u16*   hA = (u16*)(ws + 6 * MB);
        u16*   hB = (u16*)(ws + 30 * MB);
        float* Vff = (float*)(ws + 54 * MB);

        P3 w0 = {{QW0, KW0, VW0}}, b0 = {{Qb0, Kb0, Vb0}};
        layer0_all<<<dim3(L0G, 1, 3), 256, 0, stream>>>(x, c, w0, b0, hA, 0);

        dim3 g3(NXR / 128, HD / 128, 3);
        {
            P3 b = {{Qbh + 0 * HD, Kbh + 0 * HD, Vbh + 0 * HD}};
            gemm_bt_multi<1><<<g3, 256, 0, stream>>>(hA, wT + 0 * 3 * WTN, WTN, b, hB);
        }
        {
            P3 b = {{Qbh + 1 * HD, Kbh + 1 * HD, Vbh + 1 * HD}};
            gemm_bt_multi<1><<<g3, 256, 0, stream>>>(hB, wT + 1 * 3 * WTN, WTN, b, hA);
        }
        {
            P3 b = {{Qbh + 2 * HD, Kbh + 2 * HD, Vbh + 2 * HD}};
            gemm_bt_multi<1><<<g3, 256, 0, stream>>>(hA, wT + 2 * 3 * WTN, WTN, b, hB);
        }
        {
            P3 b = {{Qbo, Kbo, nullptr}};
            gemm_bt_multi<0><<<dim3(NXR / 128, HD / 128, 2), 256, 0, stream>>>(
                hB, wT + 9 * WTN, WTN, b, hA);
        }
        vout_k<<<NCR / 4, 256, 0, stream>>>(hB + 2 * NET, VWo, Vbo, Vff);

        Qb = hA; Kb = hA + NET; Vf = Vff;
    } else {
        // ================= two-phase fallback (proven 38.1 MB) =================
        u16*   R1 = (u16*)(ws + 6 * MB);
        u16*   R2 = (u16*)(ws + 22 * MB);
        float* Vff = (float*)(ws + 38 * MB);

        {
            P3 w0 = {{VW0, nullptr, nullptr}}, b0 = {{Vb0, nullptr, nullptr}};
            layer0_all<<<dim3(L0G, 1, 1), 256, 0, stream>>>(x, c, w0, b0, R1, 2);
        }
        dim3 gv(NXR / 128, HD / 128, 1);
        {
            P3 b = {{Vbh + 0 * HD, nullptr, nullptr}};
            gemm_bt_multi<1><<<gv, 256, 0, stream>>>(R1, wT + (0 * 3 + 2) * WTN, 0, b, R2);
        }
        {
            P3 b = {{Vbh + 1 * HD, nullptr, nullptr}};
            gemm_bt_multi<1><<<gv, 256, 0, stream>>>(R2, wT + (1 * 3 + 2) * WTN, 0, b, R1);
        }
        {
            P3 b = {{Vbh + 2 * HD, nullptr, nullptr}};
            gemm_bt_multi<1><<<gv, 256, 0, stream>>>(R1, wT + (2 * 3 + 2) * WTN, 0, b, R2);
        }
        vout_k<<<NCR / 4, 256, 0, stream>>>(R2, VWo, Vbo, Vff);

        {
            P3 w0 = {{QW0, KW0, nullptr}}, b0 = {{Qb0, Kb0, nullptr}};
            layer0_all<<<dim3(L0G, 1, 2), 256, 0, stream>>>(x, c, w0, b0, R1, 0);
        }
        dim3 gqk(NXR / 128, HD / 128, 2);
        {
            P3 b = {{Qbh + 0 * HD, Kbh + 0 * HD, nullptr}};
            gemm_bt_multi<1><<<gqk, 256, 0, stream>>>(R1, wT + 0 * 3 * WTN, WTN, b, R2);
        }
        {
            P3 b = {{Qbh + 1 * HD, Kbh + 1 * HD, nullptr}};
            gemm_bt_multi<1><<<gqk, 256, 0, stream>>>(R2, wT + 1 * 3 * WTN, WTN, b, R1);
        }
        {
            P3 b = {{Qbh + 2 * HD, Kbh + 2 * HD, nullptr}};
            gemm_bt_multi<1><<<gqk, 256, 0, stream>>>(R1, wT + 2 * 3 * WTN, WTN, b, R2);
        }
        {
            P3 b = {{Qbo, Kbo, nullptr}};
            gemm_bt_multi<0><<<gqk, 256, 0, stream>>>(R2, wT + 9 * WTN, WTN, b, R1);
        }
        Qb = R1; Kb = R1 + NET; Vf = Vff;
    }

    // ---- attention ----
    hipMemsetAsync(d_out, 0, (size_t)out_size * sizeof(float), stream);
    attn_mfma<<<dim3(NXR / 128, NCR / 128 / JT), 256, 0, stream>>>(
        Qb, Kb, Vf, (float*)d_out);
}